// Round 11
// baseline (140.083 us; speedup 1.0000x reference)
//
#include <hip/hip_runtime.h>
#include <math.h>

#define HH 512
#define PP 256
#define LL 4096
#define NB 8
#define BM 128
#define BN 128
#define BK 64
#define KTILES (HH / BK)

typedef __attribute__((ext_vector_type(4))) float f32x4;
typedef __attribute__((ext_vector_type(8))) __bf16 bf16x8;
typedef __attribute__((ext_vector_type(4))) unsigned short us4;
typedef __attribute__((ext_vector_type(8))) unsigned short us8;

// ws layout:
// [0, 512KB)      M1  (2P x H) bf16  rows 0..255 Re(B_bar), 256..511 Im(B_bar)
// [512KB, 1MB)    C2  (H x 2P) bf16  cols 0..255 2Re(C), 256..511 -2Im(C)
// [1MB, 1MB+2KB)  lam (P x 2) f32
// [2MB, 2MB+32MB) Bu bf16 (NB, 2P, L), scanned in place -> xs

__device__ __forceinline__ unsigned short f2bf(float x) {
  unsigned int u = __builtin_bit_cast(unsigned int, x);
  return (unsigned short)((u + 0x7fffu + ((u >> 16) & 1u)) >> 16);
}
__device__ __forceinline__ float bf2f(unsigned short h) {
  unsigned int u = ((unsigned int)h) << 16;
  return __builtin_bit_cast(float, u);
}
__device__ __forceinline__ float gelu_exact(float x) {
  return 0.5f * x * (1.0f + erff(x * 0.70710678118654752f));
}

__global__ __launch_bounds__(256) void precompute_params(
    const float* __restrict__ Lre, const float* __restrict__ Lim,
    const float* __restrict__ Bmat, const float* __restrict__ Cmat,
    const float* __restrict__ logstep,
    unsigned short* __restrict__ M1, unsigned short* __restrict__ C2,
    float* __restrict__ lam)
{
  const int p = blockIdx.x;
  const int t = threadIdx.x;
  const float re = Lre[p], im = Lim[p];
  const float step = expf(logstep[p]);
  const float er  = expf(re * step);
  const float lbr = er * cosf(im * step);
  const float lbi = er * sinf(im * step);
  if (t == 0) { lam[2*p] = lbr; lam[2*p+1] = lbi; }
  const float den = re*re + im*im;
  const float nr = lbr - 1.0f, ni = lbi;
  const float gr = (nr*re + ni*im) / den;
  const float gi = (ni*re - nr*im) / den;
  for (int h = t; h < HH; h += 256) {
    const float br = Bmat[(p*HH + h)*2 + 0];
    const float bi = Bmat[(p*HH + h)*2 + 1];
    M1[p*HH + h]        = f2bf(gr*br - gi*bi);   // Re(B_bar)
    M1[(PP+p)*HH + h]   = f2bf(gr*bi + gi*br);   // Im(B_bar)
    const float cr = Cmat[(h*PP + p)*2 + 0];
    const float ci = Cmat[(h*PP + p)*2 + 1];
    C2[h*(2*PP) + p]      = f2bf( 2.0f * cr);
    C2[h*(2*PP) + PP + p] = f2bf(-2.0f * ci);
  }
}

// Fused NN-GEMM v3: C[b](512x4096) = A(512x512, k-contig bf16) x Bsrc[b](512k x 4096n)
// Key change vs R10: A operand never touches LDS — each lane loads its MFMA
// fragment directly from global/L2 (A is 512KB, L2-resident, k-contiguous).
// LDS holds only B (dbuf 2 x 128n x 64k = 32 KiB), halving LDS traffic.
// BK=64 -> 8 K-steps, ONE raw barrier per step (lgkmcnt only; A(t+1)/B(t+1)
// global loads stay in flight across it). B staged via registers with an
// 8-row x 4-col per-thread transpose, written as FULL 16B slots (b128) using
// the R4-verified 8-slot XOR swizzle: slot_stored = ko ^ (n2&7), read back at
// (kk*4+lg) ^ (lr&7)  (n2&7 == lr&7 on the read side).
template<bool SRCF32, bool EPI>
__global__ __launch_bounds__(256, 4) void s5_gemm_fused(
    const unsigned short* __restrict__ A,
    const void* __restrict__ Bsrc,
    void* __restrict__ Cout,
    const float* __restrict__ Dv,
    const float* __restrict__ Ug)
{
  // XCD-aware bijective swizzle of flattened block id (nwg = 1024, %8==0)
  const int nbx = LL / BN;              // 32
  const int nby = HH / BM;              // 4
  const int nwg = nbx * nby * NB;       // 1024
  const int hw  = blockIdx.x + nbx * (blockIdx.y + nby * blockIdx.z);
  const int bid = (hw & 7) * (nwg >> 3) + (hw >> 3);
  const int bx = bid % nbx;
  const int by = (bid / nbx) % nby;
  const int b  = bid / (nbx * nby);

  const int n0 = bx * BN;
  const int m0 = by * BM;
  const int tid  = threadIdx.x;
  const int lane = tid & 63;
  const int w    = tid >> 6;
  const int lr = lane & 15, lg = lane >> 4;
  const int wm = (w >> 1) * 64, wn = (w & 1) * 64;

  // B double-buffer, 16 KiB each; unioned with the [128][128] bf16 C-tile
  __shared__ __align__(16) unsigned short LB[2 * BN * BK];   // 32 KiB
#define BSEL(s) (LB + (s) * BN * BK)

  f32x4 acc[4][4];
#pragma unroll
  for (int i = 0; i < 4; ++i)
#pragma unroll
    for (int j = 0; j < 4; ++j) acc[i][j] = f32x4{0.0f, 0.0f, 0.0f, 0.0f};

  // B staging decomposition: nq = n-quad (4 n's), ko = k-oct (8 k's)
  const int nq = tid & 31;
  const int ko = tid >> 5;

  const float*          BsF = (const float*)Bsrc          + (size_t)b * HH * LL;
  const unsigned short* BsH = (const unsigned short*)Bsrc + (size_t)b * HH * LL;

  f32x4 bv[8];  // G1: f32 source regs (8 k-rows x 4 n)
  us4   bh[8];  // G2: bf16 source regs

  // A fragment base: row = m0 + wm + f*16 + lr, 16B at k0 + (kk*4+lg)*8
  const unsigned short* Arow = A + (size_t)(m0 + wm + lr) * HH;
  bf16x8 aF[4][2];

#define A_LOAD(k0)                                                             \
  {                                                                            \
    _Pragma("unroll")                                                          \
    for (int f = 0; f < 4; ++f)                                                \
      _Pragma("unroll")                                                        \
      for (int kk = 0; kk < 2; ++kk)                                           \
        aF[f][kk] = *(const bf16x8*)(Arow + (size_t)(f * 16) * HH + (k0) +     \
                                     (kk * 4 + lg) * 8);                       \
  }

#define B_LOAD(k0)                                                             \
  {                                                                            \
    _Pragma("unroll")                                                          \
    for (int r = 0; r < 8; ++r) {                                              \
      if (SRCF32)                                                              \
        bv[r] = *(const f32x4*)(BsF + (size_t)((k0) + ko * 8 + r) * LL + n0 + nq * 4); \
      else                                                                     \
        bh[r] = *(const us4*)(BsH + (size_t)((k0) + ko * 8 + r) * LL + n0 + nq * 4);   \
    }                                                                          \
  }

  // full-slot b128 writes: slot = ko ^ (n2&7)
#define B_WRITE(sel)                                                           \
  {                                                                            \
    _Pragma("unroll")                                                          \
    for (int j = 0; j < 4; ++j) {                                              \
      const int n2 = nq * 4 + j;                                               \
      us8 wv;                                                                  \
      _Pragma("unroll")                                                        \
      for (int r = 0; r < 8; ++r)                                              \
        wv[r] = SRCF32 ? f2bf(bv[r][j]) : bh[r][j];                            \
      *(us8*)&BSEL(sel)[n2 * BK + ((ko ^ (n2 & 7)) * 8)] = wv;                 \
    }                                                                          \
  }

  // prologue: tile 0 staged, aF(0) loaded, full drain once
  B_LOAD(0);
  A_LOAD(0);
  B_WRITE(0);
  __syncthreads();

  for (int t = 0; t < KTILES; ++t) {
    const int cur = t & 1;
    const bool more = (t + 1 < KTILES);
    if (more) B_LOAD((t + 1) * BK);               // 8 VMEM, oldest

    // MFMA with bF read just-in-time per fn (trims live VGPRs)
#pragma unroll
    for (int fn = 0; fn < 4; ++fn) {
      const int rb = (wn + fn * 16 + lr) * BK;
      bf16x8 bF0 = *(const bf16x8*)&BSEL(cur)[rb + ((0 * 4 + lg) ^ (lr & 7)) * 8];
      bf16x8 bF1 = *(const bf16x8*)&BSEL(cur)[rb + ((1 * 4 + lg) ^ (lr & 7)) * 8];
#pragma unroll
      for (int fm = 0; fm < 4; ++fm) {
        acc[fm][fn] = __builtin_amdgcn_mfma_f32_16x16x32_bf16(
            aF[fm][0], bF0, acc[fm][fn], 0, 0, 0);
        acc[fm][fn] = __builtin_amdgcn_mfma_f32_16x16x32_bf16(
            aF[fm][1], bF1, acc[fm][fn], 0, 0, 0);
      }
    }

    if (more) {
      A_LOAD((t + 1) * BK);                       // 8 VMEM, newest (cross barrier)
      if (cur) B_WRITE(0) else B_WRITE(1);        // waits bv only (vmcnt(8))
    }
    asm volatile("s_waitcnt lgkmcnt(0)" ::: "memory");  // ds_writes visible
    __builtin_amdgcn_sched_barrier(0);
    __builtin_amdgcn_s_barrier();
    __builtin_amdgcn_sched_barrier(0);
  }
#undef A_LOAD
#undef B_LOAD
#undef B_WRITE

  if (!EPI) {
    // bf16 C-write coalesced through the freed 32 KiB LDS
#pragma unroll
    for (int fm = 0; fm < 4; ++fm)
#pragma unroll
      for (int r = 0; r < 4; ++r) {
        const int row = wm + fm * 16 + lg * 4 + r;
#pragma unroll
        for (int fn = 0; fn < 4; ++fn) {
          const int col = wn + fn * 16 + lr;
          LB[row * 128 + col] = f2bf(acc[fm][fn][r]);
        }
      }
    __syncthreads();
    unsigned short* C = (unsigned short*)Cout + (size_t)b * HH * LL;
#pragma unroll
    for (int pass = 0; pass < 8; ++pass) {
      const int chunk = pass * 256 + tid;   // 2048 us8 chunks, 16/row
      const int row = chunk >> 4;
      const int c8  = chunk & 15;
      us8 v = *(const us8*)&LB[row * 128 + c8 * 8];
      *(us8*)(C + (size_t)(m0 + row) * LL + n0 + c8 * 8) = v;
    }
  } else {
    float* C = (float*)Cout + (size_t)b * HH * LL;
    const float* Ub = Ug + (size_t)b * HH * LL;
#pragma unroll
    for (int fm = 0; fm < 4; ++fm)
#pragma unroll
      for (int r = 0; r < 4; ++r) {
        const int row = m0 + wm + fm*16 + lg*4 + r;
        const float dv = Dv[row];
#pragma unroll
        for (int fn = 0; fn < 4; ++fn) {
          const int col = n0 + wn + fn*16 + lr;
          const float y = fmaf(dv, Ub[(size_t)row * LL + col], acc[fm][fn][r]);
          C[(size_t)row * LL + col] = gelu_exact(y);
        }
      }
  }
#undef BSEL
}

// chunked parallel scan per (b,p): x_l = lam*x_{l-1} + Bu_l (complex), bf16 in place.
// Intra-wave affine scan via __shfl_up (6 rounds) + 1-barrier cross-wave combine.
__global__ __launch_bounds__(256) void s5_scan(
    unsigned short* __restrict__ Bu, const float* __restrict__ lam)
{
  const int p = blockIdx.x;
  const int b = blockIdx.y;
  const int t = threadIdx.x;
  const int lane = t & 63;
  const int w    = t >> 6;
  unsigned short* rowr = Bu + ((size_t)b*2*PP + p)      * LL;
  unsigned short* rowi = Bu + ((size_t)b*2*PP + PP + p) * LL;

  const float lre = lam[2*p], lim = lam[2*p+1];

  float br[16], bi[16];
  {
    us8 v0 = *(const us8*)&rowr[t*16];
    us8 v1 = *(const us8*)&rowr[t*16 + 8];
    us8 w0 = *(const us8*)&rowi[t*16];
    us8 w1 = *(const us8*)&rowi[t*16 + 8];
#pragma unroll
    for (int j = 0; j < 8; ++j) {
      br[j] = bf2f(v0[j]); br[8+j] = bf2f(v1[j]);
      bi[j] = bf2f(w0[j]); bi[8+j] = bf2f(w1[j]);
    }
  }

  float xr = 0.0f, xi = 0.0f;
#pragma unroll
  for (int j = 0; j < 16; ++j) {
    const float nr = fmaf(lre, xr, fmaf(-lim, xi, br[j]));
    const float ni = fmaf(lre, xi, fmaf( lim, xr, bi[j]));
    xr = nr; xi = ni;
  }

  float mre = lre, mim = lim;
#pragma unroll
  for (int s = 0; s < 4; ++s) {
    const float n2 = mre*mre - mim*mim;
    mim = 2.0f*mre*mim; mre = n2;
  }

  float Sr = xr, Si = xi;
  float pwr[6], pwi[6];
#pragma unroll
  for (int rnd = 0; rnd < 6; ++rnd) {
    pwr[rnd] = mre; pwi[rnd] = mim;
    const int off = 1 << rnd;
    const float vr = __shfl_up(Sr, off);
    const float vi = __shfl_up(Si, off);
    if (lane >= off) {
      Sr = fmaf(mre, vr, fmaf(-mim, vi, Sr));
      Si = fmaf(mre, vi, fmaf( mim, vr, Si));
    }
    const float n2 = mre*mre - mim*mim;
    mim = 2.0f*mre*mim; mre = n2;
  }

  __shared__ float Twr[4], Twi[4];
  if (lane == 63) { Twr[w] = Sr; Twi[w] = Si; }
  __syncthreads();

  float cwr = 0.0f, cwi = 0.0f;
  for (int v = 0; v < w; ++v) {
    const float nr = fmaf(mre, cwr, fmaf(-mim, cwi, Twr[v]));
    const float ni = fmaf(mre, cwi, fmaf( mim, cwr, Twi[v]));
    cwr = nr; cwi = ni;
  }

  float Er = __shfl_up(Sr, 1);
  float Ei = __shfl_up(Si, 1);
  if (lane == 0) { Er = 0.0f; Ei = 0.0f; }

  float plr = 1.0f, pli = 0.0f;
#pragma unroll
  for (int rnd = 0; rnd < 6; ++rnd) {
    if ((lane >> rnd) & 1) {
      const float nr = plr*pwr[rnd] - pli*pwi[rnd];
      const float ni = plr*pwi[rnd] + pli*pwr[rnd];
      plr = nr; pli = ni;
    }
  }

  const float cr = Er + plr*cwr - pli*cwi;
  const float ci = Ei + plr*cwi + pli*cwr;

  xr = cr; xi = ci;
  us8 o0, o1, o2, o3;
#pragma unroll
  for (int j = 0; j < 16; ++j) {
    const float nr = fmaf(lre, xr, fmaf(-lim, xi, br[j]));
    const float ni = fmaf(lre, xi, fmaf( lim, xr, bi[j]));
    xr = nr; xi = ni;
    if (j < 8) { o0[j] = f2bf(xr); o2[j] = f2bf(xi); }
    else       { o1[j-8] = f2bf(xr); o3[j-8] = f2bf(xi); }
  }
  *(us8*)&rowr[t*16]     = o0;
  *(us8*)&rowr[t*16 + 8] = o1;
  *(us8*)&rowi[t*16]     = o2;
  *(us8*)&rowi[t*16 + 8] = o3;
}

extern "C" void kernel_launch(void* const* d_in, const int* in_sizes, int n_in,
                              void* d_out, int out_size, void* d_ws, size_t ws_size,
                              hipStream_t stream) {
  (void)in_sizes; (void)n_in; (void)out_size; (void)ws_size;
  const float* in_seq = (const float*)d_in[0];
  const float* Lre    = (const float*)d_in[1];
  const float* Lim    = (const float*)d_in[2];
  const float* Bm     = (const float*)d_in[3];
  const float* Cm     = (const float*)d_in[4];
  const float* Dv     = (const float*)d_in[5];
  const float* ls     = (const float*)d_in[6];
  float* out = (float*)d_out;

  char* ws = (char*)d_ws;
  unsigned short* M1  = (unsigned short*)(ws);
  unsigned short* C2  = (unsigned short*)(ws + (512u << 10));
  float*          lam = (float*)(ws + (1u << 20));
  unsigned short* Bu  = (unsigned short*)(ws + (2u << 20));   // 32 MiB

  precompute_params<<<dim3(PP), dim3(256), 0, stream>>>(Lre, Lim, Bm, Cm, ls, M1, C2, lam);

  dim3 gg(LL/BN, HH/BM, NB);
  // G1: Bu = M1 x u   (u f32, K-strided -> fused transpose staging)
  s5_gemm_fused<true, false><<<gg, dim3(256), 0, stream>>>(M1, in_seq, Bu, nullptr, nullptr);

  s5_scan<<<dim3(PP, NB), dim3(256), 0, stream>>>(Bu, lam);

  // G2: out = gelu(C2 x xs + D*u)   (xs bf16 in Bu layout)
  s5_gemm_fused<false, true><<<gg, dim3(256), 0, stream>>>(C2, Bu, out, Dv, in_seq);
}